// Round 1
// 1914.394 us; speedup vs baseline: 1.5494x; 1.5494x over previous
//
#include <hip/hip_runtime.h>

#define N_NODES   50000
#define N_EDGES   800000
#define N_GRAPHS  256
#define EMB       128
#define L_LAYERS  8
#define N_CLASSES 10
#define BN_EPS    1e-5f
#define NEG_SLOPE 0.01f
#define BM 64
#define NBLK ((N_NODES + BM - 1) / BM)   // 782 mlp blocks

// ---------------------------------------------------------------------------
// CSR build
// ---------------------------------------------------------------------------
__global__ void deg_kernel(const int* __restrict__ ei, int* __restrict__ deg) {
    int e = blockIdx.x * 256 + threadIdx.x;
    if (e < N_EDGES) atomicAdd(&deg[ei[N_EDGES + e]], 1);
}

__global__ void scan_kernel(const int* __restrict__ deg,
                            int* __restrict__ rowptr, int* __restrict__ cursor) {
    __shared__ int sums[256];
    __shared__ int offs[257];
    int t = threadIdx.x;
    const int chunk = (N_NODES + 255) / 256;  // 196
    int start = t * chunk;
    int end   = start + chunk; if (end > N_NODES) end = N_NODES;
    int s = 0;
    for (int i = start; i < end; ++i) s += deg[i];
    sums[t] = s;
    __syncthreads();
    if (t == 0) {
        int a = 0;
        for (int i = 0; i < 256; ++i) { offs[i] = a; a += sums[i]; }
        offs[256] = a;
    }
    __syncthreads();
    int a = offs[t];
    for (int i = start; i < end; ++i) {
        rowptr[i] = a; cursor[i] = a; a += deg[i];
    }
    if (t == 255) rowptr[N_NODES] = offs[256];
}

__global__ void scatter_kernel(const int* __restrict__ ei,
                               int* __restrict__ cursor, int* __restrict__ csr) {
    int e = blockIdx.x * 256 + threadIdx.x;
    if (e < N_EDGES) {
        int d = ei[N_EDGES + e];
        int s = ei[e];
        int p = atomicAdd(&cursor[d], 1);
        csr[p] = s;
    }
}

// Deterministic adjacency: sort each node's neighbor list.
__global__ void sort_adj_kernel(const int* __restrict__ rowptr, int* __restrict__ csr) {
    int node = blockIdx.x * 256 + threadIdx.x;
    if (node >= N_NODES) return;
    int beg = rowptr[node];
    int end = rowptr[node + 1];
    for (int i = beg + 1; i < end; ++i) {
        int v = csr[i];
        int j = i - 1;
        while (j >= beg && csr[j] > v) { csr[j + 1] = csr[j]; --j; }
        csr[j + 1] = v;
    }
}

// ---------------------------------------------------------------------------
// GIN aggregate: hpre[i] = x[i] + sum_{j->i} x[j]  (deterministic csr order,
// sequential adds preserved bitwise; unroll-2 only widens the load window)
// ---------------------------------------------------------------------------
__global__ __launch_bounds__(256) void agg_kernel(
        const float* __restrict__ x, const int* __restrict__ rowptr,
        const int* __restrict__ csr, float* __restrict__ hpre) {
    int lane = threadIdx.x & 63;
    int node = __builtin_amdgcn_readfirstlane(blockIdx.x * 4 + (threadIdx.x >> 6));
    if (node >= N_NODES) return;
    int beg = rowptr[node];
    int end = rowptr[node + 1];
    const float2* xp = (const float2*)x;
    float2 acc = xp[(size_t)node * 64 + lane];
    int e = beg;
    for (; e + 1 < end; e += 2) {
        int s0 = csr[e];
        int s1 = csr[e + 1];
        float2 v0 = xp[(size_t)s0 * 64 + lane];
        float2 v1 = xp[(size_t)s1 * 64 + lane];
        acc.x += v0.x; acc.y += v0.y;   // keep exact sequential order
        acc.x += v1.x; acc.y += v1.y;
    }
    if (e < end) {
        int s0 = csr[e];
        float2 v0 = xp[(size_t)s0 * 64 + lane];
        acc.x += v0.x; acc.y += v0.y;
    }
    ((float2*)hpre)[(size_t)node * 64 + lane] = acc;
}

// ---------------------------------------------------------------------------
// Fused MLP: H = leaky(HB @ W1 + b1) @ W2 + b2 (in place) + per-block BN partials
// Column mapping per thread: cols {4tx+j, 64+4tx+j} -> Ws b128 reads are
// stride-4tx (2-way bank aliasing = free) instead of stride-8tx (4-way).
// ---------------------------------------------------------------------------
__global__ __launch_bounds__(256) void mlp_kernel(
        float* __restrict__ HB,
        const float* __restrict__ W1, const float* __restrict__ b1,
        const float* __restrict__ W2, const float* __restrict__ b2,
        float* __restrict__ pstat) {
    __shared__ float As[BM][EMB + 4];
    __shared__ float Ws[32][EMB];

    int t   = threadIdx.x;
    int tx  = t & 15;
    int ty  = t >> 4;
    int row0 = blockIdx.x * BM;

    {
        const float4* Ag = (const float4*)HB;
        #pragma unroll
        for (int rep = 0; rep < 8; ++rep) {
            int v  = t + rep * 256;
            int r  = v >> 5;
            int c4 = v & 31;
            int gr = row0 + r;
            float4 val = (gr < N_NODES) ? Ag[(size_t)gr * 32 + c4]
                                        : make_float4(0.f, 0.f, 0.f, 0.f);
            *(float4*)&As[r][c4 * 4] = val;
        }
    }

    float acc[4][8];
    #pragma unroll
    for (int i = 0; i < 4; ++i)
        #pragma unroll
        for (int j = 0; j < 8; ++j) acc[i][j] = 0.f;

    // phase 1: T = leaky(A @ W1 + b1)
    for (int kk = 0; kk < EMB; kk += 32) {
        __syncthreads();
        const float4* Wg = (const float4*)(W1 + kk * EMB);
        #pragma unroll
        for (int rep = 0; rep < 4; ++rep) {
            int v = t + rep * 256;
            *(float4*)&Ws[v >> 5][(v & 31) * 4] = Wg[v];
        }
        __syncthreads();
        #pragma unroll 4
        for (int k2 = 0; k2 < 32; ++k2) {
            float a[4], b[8];
            #pragma unroll
            for (int i = 0; i < 4; ++i) a[i] = As[ty * 4 + i][kk + k2];
            float4 bb0 = *(float4*)&Ws[k2][tx * 4];
            float4 bb1 = *(float4*)&Ws[k2][64 + tx * 4];
            b[0]=bb0.x; b[1]=bb0.y; b[2]=bb0.z; b[3]=bb0.w;
            b[4]=bb1.x; b[5]=bb1.y; b[6]=bb1.z; b[7]=bb1.w;
            #pragma unroll
            for (int i = 0; i < 4; ++i)
                #pragma unroll
                for (int j = 0; j < 8; ++j) acc[i][j] += a[i] * b[j];
        }
    }

    __syncthreads();
    #pragma unroll
    for (int j = 0; j < 8; ++j) {
        int c = (j < 4) ? (tx * 4 + j) : (64 + tx * 4 + (j - 4));
        float bias = b1[c];
        #pragma unroll
        for (int i = 0; i < 4; ++i) {
            float v = acc[i][j] + bias;
            As[ty * 4 + i][c] = (v > 0.f) ? v : NEG_SLOPE * v;
            acc[i][j] = 0.f;
        }
    }

    // phase 2: H = T @ W2 + b2
    for (int kk = 0; kk < EMB; kk += 32) {
        __syncthreads();
        const float4* Wg = (const float4*)(W2 + kk * EMB);
        #pragma unroll
        for (int rep = 0; rep < 4; ++rep) {
            int v = t + rep * 256;
            *(float4*)&Ws[v >> 5][(v & 31) * 4] = Wg[v];
        }
        __syncthreads();
        #pragma unroll 4
        for (int k2 = 0; k2 < 32; ++k2) {
            float a[4], b[8];
            #pragma unroll
            for (int i = 0; i < 4; ++i) a[i] = As[ty * 4 + i][kk + k2];
            float4 bb0 = *(float4*)&Ws[k2][tx * 4];
            float4 bb1 = *(float4*)&Ws[k2][64 + tx * 4];
            b[0]=bb0.x; b[1]=bb0.y; b[2]=bb0.z; b[3]=bb0.w;
            b[4]=bb1.x; b[5]=bb1.y; b[6]=bb1.z; b[7]=bb1.w;
            #pragma unroll
            for (int i = 0; i < 4; ++i)
                #pragma unroll
                for (int j = 0; j < 8; ++j) acc[i][j] += a[i] * b[j];
        }
    }

    // epilogue: bias, store H, per-column block-partial stats
    float csum[8], csq[8];
    #pragma unroll
    for (int j = 0; j < 8; ++j) { csum[j] = 0.f; csq[j] = 0.f; }

    #pragma unroll
    for (int i = 0; i < 4; ++i) {
        int gr = row0 + ty * 4 + i;
        if (gr < N_NODES) {
            float tmp[8];
            #pragma unroll
            for (int j = 0; j < 8; ++j) {
                int c = (j < 4) ? (tx * 4 + j) : (64 + tx * 4 + (j - 4));
                float v = acc[i][j] + b2[c];
                tmp[j] = v;
                csum[j] += v;
                csq[j]  += v * v;
            }
            float4 o0, o1;
            o0.x=tmp[0]; o0.y=tmp[1]; o0.z=tmp[2]; o0.w=tmp[3];
            o1.x=tmp[4]; o1.y=tmp[5]; o1.z=tmp[6]; o1.w=tmp[7];
            *(float4*)&HB[(size_t)gr * EMB + tx * 4]      = o0;
            *(float4*)&HB[(size_t)gr * EMB + 64 + tx * 4] = o1;
        }
    }

    // reduce stats across ty in LDS, write interleaved per-block partials
    float* red = &Ws[0][0];
    __syncthreads();
    #pragma unroll
    for (int j = 0; j < 8; ++j) {
        int c = (j < 4) ? (tx * 4 + j) : (64 + tx * 4 + (j - 4));
        red[ty * EMB + c] = csum[j];
    }
    __syncthreads();
    float s1 = 0.f;
    if (t < EMB) {
        #pragma unroll
        for (int r = 0; r < 16; ++r) s1 += red[r * EMB + t];
    }
    __syncthreads();
    #pragma unroll
    for (int j = 0; j < 8; ++j) {
        int c = (j < 4) ? (tx * 4 + j) : (64 + tx * 4 + (j - 4));
        red[ty * EMB + c] = csq[j];
    }
    __syncthreads();
    if (t < EMB) {
        float s2 = 0.f;
        #pragma unroll
        for (int r = 0; r < 16; ++r) s2 += red[r * EMB + t];
        float2 o; o.x = s1; o.y = s2;
        *(float2*)&pstat[(size_t)blockIdx.x * 256 + 2 * t] = o;
    }
}

// Fixed-order reduction of per-block partials -> mu / inv (same expressions
// as the previous finalize: bitwise-identical results)
__global__ __launch_bounds__(128) void bn_stats_kernel(
        const float* __restrict__ pstat,
        float* __restrict__ mu_out, float* __restrict__ inv_out) {
    int t = threadIdx.x;
    float s = 0.f, q = 0.f;
    for (int b = 0; b < NBLK; ++b) {
        float2 v = *(const float2*)&pstat[(size_t)b * 256 + 2 * t];
        s += v.x;
        q += v.y;
    }
    const float invN = 1.f / (float)N_NODES;
    float mu  = s * invN;
    float var = q * invN - mu * mu;
    mu_out[t]  = mu;
    inv_out[t] = rsqrtf(var + BN_EPS);
}

// ---------------------------------------------------------------------------
// BatchNorm + gumbel-argmax one-hot + graph max + next-x
// wave-per-node: 2 features/lane, shuffle-butterfly argmax, no LDS/syncs
// ---------------------------------------------------------------------------
__global__ __launch_bounds__(256) void finalize_kernel(
        const float* __restrict__ h,
        const float* __restrict__ mu_v, const float* __restrict__ inv_v,
        const float* __restrict__ gamma, const float* __restrict__ beta,
        const float* __restrict__ gumbel_l, const int* __restrict__ batch,
        float* __restrict__ nc_out, float* __restrict__ gc_out,
        float* __restrict__ xnext) {
    int lane = threadIdx.x & 63;
    int node = blockIdx.x * 4 + (threadIdx.x >> 6);

    float2 hv  = ((const float2*)h)[(size_t)node * 64 + lane];
    float2 mu2 = ((const float2*)mu_v)[lane];
    float2 iv2 = ((const float2*)inv_v)[lane];
    float2 g2  = ((const float2*)gamma)[lane];
    float2 be2 = ((const float2*)beta)[lane];
    float2 gm  = ((const float2*)gumbel_l)[(size_t)node * 64 + lane];

    // identical arithmetic to previous version: (h - mu) * inv * gamma + beta
    float hb0 = (hv.x - mu2.x) * iv2.x * g2.x + be2.x;
    float hb1 = (hv.y - mu2.y) * iv2.y * g2.y + be2.y;
    float y0 = hb0 + gm.x;   // TAU == 1.0
    float y1 = hb1 + gm.y;

    float bv; int bi;
    if (y1 > y0) { bv = y1; bi = 2 * lane + 1; }
    else         { bv = y0; bi = 2 * lane; }
    #pragma unroll
    for (int off = 32; off > 0; off >>= 1) {
        float ov = __shfl_xor(bv, off);
        int   oi = __shfl_xor(bi, off);
        if (ov > bv || (ov == bv && oi < bi)) { bv = ov; bi = oi; }
    }

    float2 nc;
    nc.x = (bi == 2 * lane)     ? 1.0f : 0.0f;
    nc.y = (bi == 2 * lane + 1) ? 1.0f : 0.0f;
    ((float2*)nc_out)[(size_t)node * 64 + lane] = nc;

    float2 xn;
    xn.x = (hb0 > 0.f) ? hb0 : NEG_SLOPE * hb0;
    xn.y = (hb1 > 0.f) ? hb1 : NEG_SLOPE * hb1;
    ((float2*)xnext)[(size_t)node * 64 + lane] = xn;

    // device-scope atomic: cross-XCD-safe idempotent write
    if (lane == 0) atomicExch(&gc_out[(size_t)batch[node] * EMB + bi], 1.0f);
}

// ---------------------------------------------------------------------------
// logits = gc_last @ dense_W + dense_b
// ---------------------------------------------------------------------------
__global__ __launch_bounds__(128) void logits_kernel(
        const float* __restrict__ gc, const float* __restrict__ W,
        const float* __restrict__ b, float* __restrict__ out) {
    __shared__ float row[EMB];
    int g = blockIdx.x;
    int t = threadIdx.x;
    row[t] = gc[g * EMB + t];
    __syncthreads();
    if (t < N_CLASSES) {
        float acc = b[t];
        for (int k = 0; k < EMB; ++k) acc += row[k] * W[k * N_CLASSES + t];
        out[g * N_CLASSES + t] = acc;
    }
}

// ---------------------------------------------------------------------------
extern "C" void kernel_launch(void* const* d_in, const int* in_sizes, int n_in,
                              void* d_out, int out_size, void* d_ws, size_t ws_size,
                              hipStream_t stream) {
    const float* x_in    = (const float*)d_in[0];
    const int*   ei      = (const int*)  d_in[1];
    const int*   batch   = (const int*)  d_in[2];
    const float* W1      = (const float*)d_in[3];
    const float* b1      = (const float*)d_in[4];
    const float* W2      = (const float*)d_in[5];
    const float* b2      = (const float*)d_in[6];
    const float* gamma   = (const float*)d_in[7];
    const float* beta    = (const float*)d_in[8];
    const float* gumbel  = (const float*)d_in[9];
    const float* dW      = (const float*)d_in[10];
    const float* db      = (const float*)d_in[11];

    float* out = (float*)d_out;
    const size_t NC_OFF = (size_t)N_GRAPHS * N_CLASSES;
    const size_t GC_OFF = NC_OFF + (size_t)L_LAYERS * N_NODES * EMB;
    float* logits_out = out;
    float* nc_out     = out + NC_OFF;
    float* gc_out     = out + GC_OFF;

    // workspace layout
    float* xbuf    = (float*)d_ws;                    // 6.4M floats
    float* hbuf    = xbuf + (size_t)N_NODES * EMB;    // 6.4M floats
    float* pstat   = hbuf + (size_t)N_NODES * EMB;    // NBLK*256 (sum/sq interleaved)
    float* mu_v    = pstat + (size_t)NBLK * 256;      // 128
    float* inv_v   = mu_v + EMB;                      // 128
    int*   rowptr  = (int*)(inv_v + EMB);             // 50001
    int*   cursor  = rowptr + (N_NODES + 1);          // 50000
    int*   csr     = cursor + N_NODES;                // 800000
    int*   deg     = csr + N_EDGES;                   // 50000

    // CSR build (deterministic after per-node sort)
    hipMemsetAsync(deg, 0, N_NODES * sizeof(int), stream);
    deg_kernel<<<(N_EDGES + 255) / 256, 256, 0, stream>>>(ei, deg);
    scan_kernel<<<1, 256, 0, stream>>>(deg, rowptr, cursor);
    scatter_kernel<<<(N_EDGES + 255) / 256, 256, 0, stream>>>(ei, cursor, csr);
    sort_adj_kernel<<<(N_NODES + 255) / 256, 256, 0, stream>>>(rowptr, csr);

    hipMemsetAsync(gc_out, 0,
                   (size_t)L_LAYERS * N_GRAPHS * EMB * sizeof(float), stream);

    for (int l = 0; l < L_LAYERS; ++l) {
        const float* xsrc = (l == 0) ? x_in : xbuf;
        agg_kernel<<<(N_NODES + 3) / 4, 256, 0, stream>>>(xsrc, rowptr, csr, hbuf);
        mlp_kernel<<<NBLK, 256, 0, stream>>>(
            hbuf,
            W1 + (size_t)l * EMB * EMB, b1 + (size_t)l * EMB,
            W2 + (size_t)l * EMB * EMB, b2 + (size_t)l * EMB,
            pstat);
        bn_stats_kernel<<<1, 128, 0, stream>>>(pstat, mu_v, inv_v);
        finalize_kernel<<<(N_NODES + 3) / 4, 256, 0, stream>>>(
            hbuf, mu_v, inv_v,
            gamma + (size_t)l * EMB, beta + (size_t)l * EMB,
            gumbel + (size_t)l * N_NODES * EMB, batch,
            nc_out + (size_t)l * N_NODES * EMB,
            gc_out + (size_t)l * N_GRAPHS * EMB,
            xbuf);
    }

    logits_kernel<<<N_GRAPHS, 128, 0, stream>>>(
        gc_out + (size_t)(L_LAYERS - 1) * N_GRAPHS * EMB, dW, db, logits_out);
}